// Round 8
// baseline (155.270 us; speedup 1.0000x reference)
//
#include <hip/hip_runtime.h>
#include <hip/hip_bf16.h>

// Problem constants (B=1, N=2048, D=1024, H=16, HD=64; NO=74 offsets)
#define SEQ_N 2048
#define DIM   1024
#define NHEAD 16
#define HDIM  64
#define LDQ   4096   // qkvg row stride: [q | k | v | gatepre]
#define NOFF  74     // 65 dense (0..64) + 9 dyadic
#define NDENSE 65
#define NJ    224    // 80 dense rows + 9*16 dyadic rows
#define NT    16     // n-rows per attention block
#define PST   232    // Pd row stride (padded, 16B-aligned)
#define QST   88     // Qbuf row stride (16B-aligned)

typedef __attribute__((ext_vector_type(8))) __bf16 bv8;
typedef __attribute__((ext_vector_type(4))) __bf16 bv4;
typedef __attribute__((ext_vector_type(4))) float  f32x4;

typedef __attribute__((address_space(3))) void as3_void;
typedef __attribute__((address_space(1))) void as1_void;

// async global->LDS 16B copy. LDS dest must be wave-uniform base + lane*16.
__device__ __forceinline__ void async16(const void* g, void* l) {
  __builtin_amdgcn_global_load_lds((as1_void*)(unsigned long long)g,
                                   (as3_void*)l, 16, 0, 0);
}

// ---------------------------------------------------------------------------
// fp32 -> bf16 convert, all 4 tensors in one launch (dst regions contiguous).
// ---------------------------------------------------------------------------
#define E1 (SEQ_N * DIM)            // x
#define E2 (E1 + 3 * DIM * DIM)     // + Wqkv
#define E3 (E2 + DIM * DIM)         // + Wgate
#define E4 (E3 + DIM * DIM)         // + Wout
__global__ __launch_bounds__(256) void cvt_all(
    const float* __restrict__ x, const float* __restrict__ wqkv,
    const float* __restrict__ wgate, const float* __restrict__ wout,
    __bf16* __restrict__ dst) {
  long i = ((long)blockIdx.x * 256 + threadIdx.x) * 4;
  if (i >= E4) return;
  const float* s; long o;
  if (i < E1)      { s = x;     o = i; }
  else if (i < E2) { s = wqkv;  o = i - E1; }
  else if (i < E3) { s = wgate; o = i - E2; }
  else             { s = wout;  o = i - E3; }
  float4 v = *(const float4*)(s + o);
  bv4 ov;
  ov[0] = (__bf16)v.x; ov[1] = (__bf16)v.y; ov[2] = (__bf16)v.z; ov[3] = (__bf16)v.w;
  *(bv4*)(dst + i) = ov;
}

// ---------------------------------------------------------------------------
// GEMM (128xBN_ tile, BK=64): C = A[MxK] * B[NoutxK]^T + bias, bf16 in, fp32
// accum, OutT out. B split at col Nsplit. m97 staging (async16 width-16).
// __launch_bounds__(256,4): cap VGPR at 128 -> 4 blocks/CU (4 independent
// barrier domains to overlap the staging drain; LDS 32 KB allows 5).
// ---------------------------------------------------------------------------
#define BM 128
#define BKG 64

template <int BN_, typename OutT>
__global__ __launch_bounds__(256, 4) void gemm_bt(
    const __bf16* __restrict__ A, const __bf16* __restrict__ B1,
    const __bf16* __restrict__ B2, const float* __restrict__ bias1,
    const float* __restrict__ bias2, int Nsplit,
    OutT* __restrict__ C, int ldc, int K) {
  __shared__ __attribute__((aligned(16))) __bf16 Asm[BM * BKG];
  __shared__ __attribute__((aligned(16))) __bf16 Bsm[BN_ * BKG];
  constexpr int NJT = BN_ / 32;            // j-tiles per wave
  constexpr int CA = BM * BKG / 8;         // A 16B-chunks
  constexpr int CB = BN_ * BKG / 8;        // B 16B-chunks
  constexpr int CPR = BKG / 8;             // chunks per row

  const int tid  = threadIdx.x;
  const int lane = tid & 63;
  const int wave = tid >> 6;
  const int wr = wave >> 1, wc = wave & 1;
  const int fr = lane & 15, fq = lane >> 4;

  const int bn0 = blockIdx.x * BN_;
  const int bm0 = blockIdx.y * BM;

  const __bf16* Bp;
  const float* biasp;
  if (bn0 < Nsplit) { Bp = B1 + (size_t)bn0 * K;            biasp = bias1 + bn0; }
  else              { Bp = B2 + (size_t)(bn0 - Nsplit) * K; biasp = bias2 + (bn0 - Nsplit); }
  const __bf16* Ap = A + (size_t)bm0 * K;

  f32x4 acc[4][NJT] = {};

  for (int kt = 0; kt < K; kt += BKG) {
    __syncthreads();
#pragma unroll
    for (int c0 = 0; c0 < CA + CB; c0 += 256) {
      int c = c0 + tid;
      if (c < CA) {
        int rr = c / CPR, qq = c % CPR;
        async16(Ap + (size_t)rr * K + kt + qq * 8, Asm + c * 8);
      } else {
        int cb = c - CA;
        int rr = cb / CPR, qq = cb % CPR;
        async16(Bp + (size_t)rr * K + kt + qq * 8, Bsm + cb * 8);
      }
    }
    __syncthreads();

#pragma unroll
    for (int kk = 0; kk < BKG / 32; ++kk) {
      bv8 af[4], bfr[NJT];
#pragma unroll
      for (int i = 0; i < 4; ++i)
        af[i] = *(const bv8*)(Asm + (wr * 64 + i * 16 + fr) * BKG + kk * 32 + fq * 8);
#pragma unroll
      for (int j = 0; j < NJT; ++j)
        bfr[j] = *(const bv8*)(Bsm + (wc * (BN_ / 2) + j * 16 + fr) * BKG + kk * 32 + fq * 8);
#pragma unroll
      for (int i = 0; i < 4; ++i)
#pragma unroll
        for (int j = 0; j < NJT; ++j)
          acc[i][j] = __builtin_amdgcn_mfma_f32_16x16x32_bf16(af[i], bfr[j], acc[i][j], 0, 0, 0);
    }
  }

#pragma unroll
  for (int i = 0; i < 4; ++i) {
#pragma unroll
    for (int j = 0; j < NJT; ++j) {
      int ccol = wc * (BN_ / 2) + j * 16 + fr;
      float b = biasp[ccol];
#pragma unroll
      for (int r = 0; r < 4; ++r) {
        int row = bm0 + wr * 64 + i * 16 + fq * 4 + r;
        C[(size_t)row * ldc + bn0 + ccol] = (OutT)(acc[i][j][r] + b);
      }
    }
  }
}

// ---------------------------------------------------------------------------
// GEMM 64x64 tile, BK=64 (gemm3: 512 blocks, low VGPR -> high co-residency).
// 4 waves in 2x2; each wave a 32x32 tile via 2x2 of 16x16x32 MFMA.
// ---------------------------------------------------------------------------
template <typename OutT>
__global__ __launch_bounds__(256) void gemm_bt64(
    const __bf16* __restrict__ A, const __bf16* __restrict__ B,
    const float* __restrict__ bias, OutT* __restrict__ C, int ldc, int K) {
  __shared__ __attribute__((aligned(16))) __bf16 Asm[64 * BKG];  // 8 KB
  __shared__ __attribute__((aligned(16))) __bf16 Bsm[64 * BKG];  // 8 KB

  const int tid  = threadIdx.x;
  const int lane = tid & 63;
  const int wave = tid >> 6;
  const int wr = wave >> 1, wc = wave & 1;
  const int fr = lane & 15, fq = lane >> 4;

  const int bn0 = blockIdx.x * 64;
  const int bm0 = blockIdx.y * 64;

  const __bf16* Ap = A + (size_t)bm0 * K;
  const __bf16* Bp = B + (size_t)bn0 * K;
  const float* biasp = bias + bn0;

  f32x4 acc[2][2] = {};

  for (int kt = 0; kt < K; kt += BKG) {
    __syncthreads();
#pragma unroll
    for (int c0 = 0; c0 < 512; c0 += 256) {
      int c = c0 + tid;
      int rr = c >> 3, qq = c & 7;
      async16(Ap + (size_t)rr * K + kt + qq * 8, Asm + c * 8);
      async16(Bp + (size_t)rr * K + kt + qq * 8, Bsm + c * 8);
    }
    __syncthreads();

#pragma unroll
    for (int kk = 0; kk < 2; ++kk) {
      bv8 af[2], bfr[2];
#pragma unroll
      for (int i = 0; i < 2; ++i)
        af[i] = *(const bv8*)(Asm + (wr * 32 + i * 16 + fr) * BKG + kk * 32 + fq * 8);
#pragma unroll
      for (int j = 0; j < 2; ++j)
        bfr[j] = *(const bv8*)(Bsm + (wc * 32 + j * 16 + fr) * BKG + kk * 32 + fq * 8);
#pragma unroll
      for (int i = 0; i < 2; ++i)
#pragma unroll
        for (int j = 0; j < 2; ++j)
          acc[i][j] = __builtin_amdgcn_mfma_f32_16x16x32_bf16(af[i], bfr[j], acc[i][j], 0, 0, 0);
    }
  }

#pragma unroll
  for (int i = 0; i < 2; ++i) {
#pragma unroll
    for (int j = 0; j < 2; ++j) {
      int ccol = wc * 32 + j * 16 + fr;
      float b = biasp[ccol];
#pragma unroll
      for (int r = 0; r < 4; ++r) {
        int row = bm0 + wr * 32 + i * 16 + fq * 4 + r;
        C[(size_t)row * ldc + bn0 + ccol] = (OutT)(acc[i][j][r] + b);
      }
    }
  }
}

// ---------------------------------------------------------------------------
// MFMA-tile attention + gate (round-4 version, verified fastest so far).
// One 256-thread block per (16-row n-tile, head).
// ---------------------------------------------------------------------------
__global__ __launch_bounds__(256) void attn_mfma(
    const __bf16* __restrict__ qkv,      // [SEQ_N x LDQ]
    const float* __restrict__ pos_bias,  // [NOFF x NHEAD]
    const int* __restrict__ offsets,     // [NOFF]
    __bf16* __restrict__ fg) {
  const int n0 = (blockIdx.x >> 4) * NT;
  const int h  = blockIdx.x & 15;
  const int tid = threadIdx.x;
  const int lane = tid & 63;
  const int w = tid >> 6;
  const int fr = lane & 15, fq = lane >> 4;

  __shared__ __attribute__((aligned(16))) __bf16 Kbuf[NJ * HDIM];   // 28672 B
  __shared__ __attribute__((aligned(16))) __bf16 Vbuf[NJ * HDIM];   // 28672 B
  __shared__ __attribute__((aligned(16))) __bf16 Qbuf[NT * QST];    // 2816 B
  __shared__ __attribute__((aligned(16))) float  Sbuf[NT][80];      // 5120 B
  __shared__ __attribute__((aligned(16))) __bf16 Pd[NT * PST];      // 7424 B
  __shared__ float inv_l[NT];

  // --- Phase 0: stage Q, zero Pd, async-stage K/V ---
  if (tid < 128) {
    int ni = tid >> 3, ch = tid & 7;
    bv8 q = *(const bv8*)(qkv + (size_t)(n0 + ni) * LDQ + h * HDIM + ch * 8);
    *(bv8*)(Qbuf + ni * QST + ch * 8) = q;
  }
#pragma unroll
  for (int c0 = 0; c0 < NT * PST / 8; c0 += 256) {
    int c = c0 + tid;
    if (c < NT * PST / 8) *(uint4*)(Pd + c * 8) = make_uint4(0, 0, 0, 0);
  }
  {
    int ch = lane & 7;
#pragma unroll
    for (int it = 0; it < 7; ++it) {
      int jbase = it * 32 + w * 8;
      int j = jbase + (lane >> 3);
      int g;
      if (j < 80) g = n0 - 64 + j;
      else { int jj = j - 80; g = n0 - offsets[NDENSE + (jj >> 4)] + (jj & 15); }
      if (g < 0) g = 0;   // clamp; masked later
      const __bf16* kg = qkv + (size_t)g * LDQ + DIM + h * HDIM + ch * 8;
      async16(kg, Kbuf + jbase * HDIM + lane * 8);
      async16(kg + DIM, Vbuf + jbase * HDIM + lane * 8);
    }
  }
  __syncthreads();

  // --- Phase 1: scores via MFMA, scatter banded entries to Sbuf ---
  for (int jb = w; jb < 14; jb += 4) {
    f32x4 acc = {};
#pragma unroll
    for (int kk = 0; kk < 2; ++kk) {
      bv8 a = *(const bv8*)(Qbuf + fr * QST + kk * 32 + fq * 8);
      bv8 b = *(const bv8*)(Kbuf + (jb * 16 + fr) * HDIM + kk * 32 + fq * 8);
      acc = __builtin_amdgcn_mfma_f32_16x16x32_bf16(a, b, acc, 0, 0, 0);
    }
    int j = jb * 16 + fr;           // Kbuf row this lane's column maps to
    if (jb < 5) {                   // dense region
      bool gvalid = (n0 - 64 + j) >= 0;
#pragma unroll
      for (int r = 0; r < 4; ++r) {
        int ni = fq * 4 + r;
        int o = ni + 64 - j;
        if (o >= 0 && o < NDENSE)
          Sbuf[ni][o] = gvalid ? acc[r] : -3.0e38f;
      }
    } else {                        // dyadic: only diagonal entries used
      int jj = j - 80;
      int s = jj >> 4, tni = jj & 15;
      int r = tni - fq * 4;
      if (r >= 0 && r < 4) {
        bool gvalid = (n0 + tni - offsets[NDENSE + s]) >= 0;
        Sbuf[tni][NDENSE + s] = gvalid ? acc[r] : -3.0e38f;
      }
    }
  }
  __syncthreads();

  // --- Phase 2: softmax (16 threads per row), banded P -> Pd (bf16) ---
  {
    int t = tid & 15, ni = tid >> 4;
    float sc5[5];
    float m = -3.0e38f;
#pragma unroll
    for (int k = 0; k < 5; ++k) {
      int o = t + k * 16;
      float v = -3.0e38f;
      if (o < NOFF) {
        float raw = Sbuf[ni][o];
        if (raw > -1.0e38f) v = raw * 0.125f + pos_bias[o * NHEAD + h];
      }
      sc5[k] = v;
      m = fmaxf(m, v);
    }
#pragma unroll
    for (int d = 1; d < 16; d <<= 1) m = fmaxf(m, __shfl_xor(m, d));
    float sum = 0.f;
#pragma unroll
    for (int k = 0; k < 5; ++k) {
      int o = t + k * 16;
      if (o < NOFF && sc5[k] > -1.0e38f) {
        float e = __expf(sc5[k] - m);
        sum += e;
        int j = (o < NDENSE) ? (ni + 64 - o) : (80 + (o - NDENSE) * 16 + ni);
        Pd[ni * PST + j] = (__bf16)e;
      }
    }
#pragma unroll
    for (int d = 1; d < 16; d <<= 1) sum += __shfl_xor(sum, d);
    if (t == 0) inv_l[ni] = 1.f / sum;
  }
  __syncthreads();

  // --- Phase 3: PV via MFMA (each wave one 16-col d-tile) + gate epilogue ---
  {
    const int db = w;
    f32x4 acc = {};
#pragma unroll
    for (int kt = 0; kt < 7; ++kt) {
      bv8 a = *(const bv8*)(Pd + fr * PST + kt * 32 + fq * 8);
      bv8 b;
#pragma unroll
      for (int jj = 0; jj < 8; ++jj)
        b[jj] = Vbuf[(kt * 32 + fq * 8 + jj) * HDIM + db * 16 + fr];
      acc = __builtin_amdgcn_mfma_f32_16x16x32_bf16(a, b, acc, 0, 0, 0);
    }
    int d = db * 16 + fr;
#pragma unroll
    for (int r = 0; r < 4; ++r) {
      int ni = fq * 4 + r;
      float o = acc[r] * inv_l[ni];
      float gp = (float)qkv[(size_t)(n0 + ni) * LDQ + 3 * DIM + h * HDIM + d];
      float gate = 1.f / (1.f + __expf(-gp));
      fg[(size_t)(n0 + ni) * DIM + h * HDIM + d] = (__bf16)(o * gate);
    }
  }
}

// ---------------------------------------------------------------------------
extern "C" void kernel_launch(void* const* d_in, const int* in_sizes, int n_in,
                              void* d_out, int out_size, void* d_ws, size_t ws_size,
                              hipStream_t stream) {
  const float* x        = (const float*)d_in[0];
  const float* Wqkv     = (const float*)d_in[1];
  const float* bqkv     = (const float*)d_in[2];
  const float* Wgate    = (const float*)d_in[3];
  const float* bgate    = (const float*)d_in[4];
  const float* Wout     = (const float*)d_in[5];
  const float* bout     = (const float*)d_in[6];
  const float* pos_bias = (const float*)d_in[7];
  const int*   offsets  = (const int*)d_in[8];
  float* out = (float*)d_out;

  // workspace layout (bf16), cvt dst regions contiguous in this order
  __bf16* xb       = (__bf16*)d_ws;                               // 2048x1024
  __bf16* Wqkvb    = xb    + (size_t)SEQ_N * DIM;                 // 3072x1024
  __bf16* Wgateb   = Wqkvb + (size_t)3 * DIM * DIM;               // 1024x1024
  __bf16* Woutb    = Wgateb + (size_t)DIM * DIM;                  // 1024x1024
  __bf16* qkvg     = Woutb + (size_t)DIM * DIM;                   // 2048x4096
  __bf16* flatgate = qkvg + (size_t)SEQ_N * LDQ;                  // 2048x1024

  // 0) fp32 -> bf16 (single launch)
  cvt_all<<<dim3(E4 / 1024), dim3(256), 0, stream>>>(x, Wqkv, Wgate, Wout, xb);

  // 1) [qkv | gate_pre] = x @ [Wqkv;Wgate]^T + [bqkv;bgate]  -> bf16 qkvg
  gemm_bt<128, __bf16><<<dim3(LDQ / 128, SEQ_N / BM), dim3(256), 0, stream>>>(
      xb, Wqkvb, Wgateb, bqkv, bgate, 3 * DIM, qkvg, LDQ, DIM);

  // 2) attention + sigmoid-gate fuse -> flatgate (bf16)
  attn_mfma<<<dim3((SEQ_N / NT) * NHEAD), dim3(256), 0, stream>>>(
      qkvg, pos_bias, offsets, flatgate);

  // 3) out = flatgate @ Wout^T + bout  -> fp32 d_out (64x64 tiles: 512 blocks)
  gemm_bt64<float><<<dim3(DIM / 64, SEQ_N / 64), dim3(256), 0, stream>>>(
      flatgate, Woutb, bout, out, DIM, DIM);
}

// Round 9
// 147.829 us; speedup vs baseline: 1.0503x; 1.0503x over previous
//
#include <hip/hip_runtime.h>
#include <hip/hip_bf16.h>

// Problem constants (B=1, N=2048, D=1024, H=16, HD=64; NO=74 offsets)
#define SEQ_N 2048
#define DIM   1024
#define NHEAD 16
#define HDIM  64
#define LDQ   4096   // qkvg row stride: [q | k | v | gatepre]
#define NOFF  74     // 65 dense (0..64) + 9 dyadic
#define NDENSE 65
#define NJ    224    // 80 dense rows + 9*16 dyadic rows
#define NT    16     // n-rows per attention block
#define PST   232    // Pd row stride (padded, 16B-aligned)
#define QST   88     // Qbuf row stride (16B-aligned)

typedef __attribute__((ext_vector_type(8))) __bf16 bv8;
typedef __attribute__((ext_vector_type(4))) __bf16 bv4;
typedef __attribute__((ext_vector_type(4))) float  f32x4;

typedef __attribute__((address_space(3))) void as3_void;
typedef __attribute__((address_space(1))) void as1_void;

// async global->LDS 16B copy. LDS dest must be wave-uniform base + lane*16.
__device__ __forceinline__ void async16(const void* g, void* l) {
  __builtin_amdgcn_global_load_lds((as1_void*)(unsigned long long)g,
                                   (as3_void*)l, 16, 0, 0);
}

// ---------------------------------------------------------------------------
// fp32 -> bf16 convert, all 4 tensors in one launch (dst regions contiguous).
// ---------------------------------------------------------------------------
#define E1 (SEQ_N * DIM)            // x
#define E2 (E1 + 3 * DIM * DIM)     // + Wqkv
#define E3 (E2 + DIM * DIM)         // + Wgate
#define E4 (E3 + DIM * DIM)         // + Wout
__global__ __launch_bounds__(256) void cvt_all(
    const float* __restrict__ x, const float* __restrict__ wqkv,
    const float* __restrict__ wgate, const float* __restrict__ wout,
    __bf16* __restrict__ dst) {
  long i = ((long)blockIdx.x * 256 + threadIdx.x) * 4;
  if (i >= E4) return;
  const float* s; long o;
  if (i < E1)      { s = x;     o = i; }
  else if (i < E2) { s = wqkv;  o = i - E1; }
  else if (i < E3) { s = wgate; o = i - E2; }
  else             { s = wout;  o = i - E3; }
  float4 v = *(const float4*)(s + o);
  bv4 ov;
  ov[0] = (__bf16)v.x; ov[1] = (__bf16)v.y; ov[2] = (__bf16)v.z; ov[3] = (__bf16)v.w;
  *(bv4*)(dst + i) = ov;
}

// ---------------------------------------------------------------------------
// GEMM (128xBN_ tile, BK=64): C = A[MxK] * B[NoutxK]^T + bias, bf16 in, fp32
// accum, OutT out. B split at col Nsplit. m97 staging (async16 width-16).
// XOR chunk-swizzle on the GLOBAL side (LDS stays contiguous for async16):
// chunk (row,qq) holds global k-chunk qq^(row&7); fragment reads use
// physical chunk (kk*4+fq)^(fr&7) -> uniform bank-group spread (2-way, free).
// ---------------------------------------------------------------------------
#define BM 128
#define BKG 64

template <int BN_, typename OutT>
__global__ __launch_bounds__(256, 4) void gemm_bt(
    const __bf16* __restrict__ A, const __bf16* __restrict__ B1,
    const __bf16* __restrict__ B2, const float* __restrict__ bias1,
    const float* __restrict__ bias2, int Nsplit,
    OutT* __restrict__ C, int ldc, int K) {
  __shared__ __attribute__((aligned(16))) __bf16 Asm[BM * BKG];
  __shared__ __attribute__((aligned(16))) __bf16 Bsm[BN_ * BKG];
  constexpr int NJT = BN_ / 32;            // j-tiles per wave
  constexpr int CA = BM * BKG / 8;         // A 16B-chunks
  constexpr int CB = BN_ * BKG / 8;        // B 16B-chunks
  constexpr int CPR = BKG / 8;             // chunks per row

  const int tid  = threadIdx.x;
  const int lane = tid & 63;
  const int wave = tid >> 6;
  const int wr = wave >> 1, wc = wave & 1;
  const int fr = lane & 15, fq = lane >> 4;
  const int fr7 = fr & 7;

  const int bn0 = blockIdx.x * BN_;
  const int bm0 = blockIdx.y * BM;

  const __bf16* Bp;
  const float* biasp;
  if (bn0 < Nsplit) { Bp = B1 + (size_t)bn0 * K;            biasp = bias1 + bn0; }
  else              { Bp = B2 + (size_t)(bn0 - Nsplit) * K; biasp = bias2 + (bn0 - Nsplit); }
  const __bf16* Ap = A + (size_t)bm0 * K;

  f32x4 acc[4][NJT] = {};

  for (int kt = 0; kt < K; kt += BKG) {
    __syncthreads();
#pragma unroll
    for (int c0 = 0; c0 < CA + CB; c0 += 256) {
      int c = c0 + tid;
      if (c < CA) {
        int rr = c / CPR, qq = c % CPR;
        int qs = qq ^ (rr & 7);
        async16(Ap + (size_t)rr * K + kt + qs * 8, Asm + c * 8);
      } else {
        int cb = c - CA;
        int rr = cb / CPR, qq = cb % CPR;
        int qs = qq ^ (rr & 7);
        async16(Bp + (size_t)rr * K + kt + qs * 8, Bsm + cb * 8);
      }
    }
    __syncthreads();

#pragma unroll
    for (int kk = 0; kk < BKG / 32; ++kk) {
      const int qs = ((kk * 4 + fq) ^ fr7) * 8;
      bv8 af[4], bfr[NJT];
#pragma unroll
      for (int i = 0; i < 4; ++i)
        af[i] = *(const bv8*)(Asm + (wr * 64 + i * 16 + fr) * BKG + qs);
#pragma unroll
      for (int j = 0; j < NJT; ++j)
        bfr[j] = *(const bv8*)(Bsm + (wc * (BN_ / 2) + j * 16 + fr) * BKG + qs);
#pragma unroll
      for (int i = 0; i < 4; ++i)
#pragma unroll
        for (int j = 0; j < NJT; ++j)
          acc[i][j] = __builtin_amdgcn_mfma_f32_16x16x32_bf16(af[i], bfr[j], acc[i][j], 0, 0, 0);
    }
  }

#pragma unroll
  for (int i = 0; i < 4; ++i) {
#pragma unroll
    for (int j = 0; j < NJT; ++j) {
      int ccol = wc * (BN_ / 2) + j * 16 + fr;
      float b = biasp[ccol];
#pragma unroll
      for (int r = 0; r < 4; ++r) {
        int row = bm0 + wr * 64 + i * 16 + fq * 4 + r;
        C[(size_t)row * ldc + bn0 + ccol] = (OutT)(acc[i][j][r] + b);
      }
    }
  }
}

// ---------------------------------------------------------------------------
// GEMM 64x64 tile, BK=64 (gemm3: 512 blocks). Same XOR chunk-swizzle.
// ---------------------------------------------------------------------------
template <typename OutT>
__global__ __launch_bounds__(256) void gemm_bt64(
    const __bf16* __restrict__ A, const __bf16* __restrict__ B,
    const float* __restrict__ bias, OutT* __restrict__ C, int ldc, int K) {
  __shared__ __attribute__((aligned(16))) __bf16 Asm[64 * BKG];  // 8 KB
  __shared__ __attribute__((aligned(16))) __bf16 Bsm[64 * BKG];  // 8 KB

  const int tid  = threadIdx.x;
  const int lane = tid & 63;
  const int wave = tid >> 6;
  const int wr = wave >> 1, wc = wave & 1;
  const int fr = lane & 15, fq = lane >> 4;
  const int fr7 = fr & 7;

  const int bn0 = blockIdx.x * 64;
  const int bm0 = blockIdx.y * 64;

  const __bf16* Ap = A + (size_t)bm0 * K;
  const __bf16* Bp = B + (size_t)bn0 * K;
  const float* biasp = bias + bn0;

  f32x4 acc[2][2] = {};

  for (int kt = 0; kt < K; kt += BKG) {
    __syncthreads();
#pragma unroll
    for (int c0 = 0; c0 < 512; c0 += 256) {
      int c = c0 + tid;
      int rr = c >> 3, qq = c & 7;
      int qs = qq ^ (rr & 7);
      async16(Ap + (size_t)rr * K + kt + qs * 8, Asm + c * 8);
      async16(Bp + (size_t)rr * K + kt + qs * 8, Bsm + c * 8);
    }
    __syncthreads();

#pragma unroll
    for (int kk = 0; kk < 2; ++kk) {
      const int qs = ((kk * 4 + fq) ^ fr7) * 8;
      bv8 af[2], bfr[2];
#pragma unroll
      for (int i = 0; i < 2; ++i)
        af[i] = *(const bv8*)(Asm + (wr * 32 + i * 16 + fr) * BKG + qs);
#pragma unroll
      for (int j = 0; j < 2; ++j)
        bfr[j] = *(const bv8*)(Bsm + (wc * 32 + j * 16 + fr) * BKG + qs);
#pragma unroll
      for (int i = 0; i < 2; ++i)
#pragma unroll
        for (int j = 0; j < 2; ++j)
          acc[i][j] = __builtin_amdgcn_mfma_f32_16x16x32_bf16(af[i], bfr[j], acc[i][j], 0, 0, 0);
    }
  }

#pragma unroll
  for (int i = 0; i < 2; ++i) {
#pragma unroll
    for (int j = 0; j < 2; ++j) {
      int ccol = wc * 32 + j * 16 + fr;
      float b = biasp[ccol];
#pragma unroll
      for (int r = 0; r < 4; ++r) {
        int row = bm0 + wr * 32 + i * 16 + fq * 4 + r;
        C[(size_t)row * ldc + bn0 + ccol] = (OutT)(acc[i][j][r] + b);
      }
    }
  }
}

// ---------------------------------------------------------------------------
// MFMA-tile attention + gate. One 256-thread block per (16-row n-tile, head).
// Kbuf staged with the same global-side XOR chunk-swizzle (row stride 128 B
// would otherwise alias all fragment rows to one bank group); Vbuf unswizzled.
// ---------------------------------------------------------------------------
__global__ __launch_bounds__(256) void attn_mfma(
    const __bf16* __restrict__ qkv,      // [SEQ_N x LDQ]
    const float* __restrict__ pos_bias,  // [NOFF x NHEAD]
    const int* __restrict__ offsets,     // [NOFF]
    __bf16* __restrict__ fg) {
  const int n0 = (blockIdx.x >> 4) * NT;
  const int h  = blockIdx.x & 15;
  const int tid = threadIdx.x;
  const int lane = tid & 63;
  const int w = tid >> 6;
  const int fr = lane & 15, fq = lane >> 4;
  const int fr7 = fr & 7;

  __shared__ __attribute__((aligned(16))) __bf16 Kbuf[NJ * HDIM];   // 28672 B
  __shared__ __attribute__((aligned(16))) __bf16 Vbuf[NJ * HDIM];   // 28672 B
  __shared__ __attribute__((aligned(16))) __bf16 Qbuf[NT * QST];    // 2816 B
  __shared__ __attribute__((aligned(16))) float  Sbuf[NT][80];      // 5120 B
  __shared__ __attribute__((aligned(16))) __bf16 Pd[NT * PST];      // 7424 B
  __shared__ float inv_l[NT];

  // --- Phase 0: stage Q, zero Pd, async-stage K (swizzled) / V (plain) ---
  if (tid < 128) {
    int ni = tid >> 3, ch = tid & 7;
    bv8 q = *(const bv8*)(qkv + (size_t)(n0 + ni) * LDQ + h * HDIM + ch * 8);
    *(bv8*)(Qbuf + ni * QST + ch * 8) = q;
  }
#pragma unroll
  for (int c0 = 0; c0 < NT * PST / 8; c0 += 256) {
    int c = c0 + tid;
    if (c < NT * PST / 8) *(uint4*)(Pd + c * 8) = make_uint4(0, 0, 0, 0);
  }
  {
    int ch = lane & 7;
    int rowin = lane >> 3;          // 0..7, equals (row index)&7
    int chs = ch ^ rowin;           // swizzled k-chunk for Kbuf
#pragma unroll
    for (int it = 0; it < 7; ++it) {
      int jbase = it * 32 + w * 8;
      int j = jbase + rowin;
      int g;
      if (j < 80) g = n0 - 64 + j;
      else { int jj = j - 80; g = n0 - offsets[NDENSE + (jj >> 4)] + (jj & 15); }
      if (g < 0) g = 0;   // clamp; masked later
      const __bf16* base = qkv + (size_t)g * LDQ + DIM + h * HDIM;
      async16(base + chs * 8, Kbuf + jbase * HDIM + lane * 8);
      async16(base + DIM + ch * 8, Vbuf + jbase * HDIM + lane * 8);
    }
  }
  __syncthreads();

  // --- Phase 1: scores via MFMA, scatter banded entries to Sbuf ---
  for (int jb = w; jb < 14; jb += 4) {
    f32x4 acc = {};
#pragma unroll
    for (int kk = 0; kk < 2; ++kk) {
      bv8 a = *(const bv8*)(Qbuf + fr * QST + kk * 32 + fq * 8);
      bv8 b = *(const bv8*)(Kbuf + (jb * 16 + fr) * HDIM + ((kk * 4 + fq) ^ fr7) * 8);
      acc = __builtin_amdgcn_mfma_f32_16x16x32_bf16(a, b, acc, 0, 0, 0);
    }
    int j = jb * 16 + fr;           // Kbuf row this lane's column maps to
    if (jb < 5) {                   // dense region
      bool gvalid = (n0 - 64 + j) >= 0;
#pragma unroll
      for (int r = 0; r < 4; ++r) {
        int ni = fq * 4 + r;
        int o = ni + 64 - j;
        if (o >= 0 && o < NDENSE)
          Sbuf[ni][o] = gvalid ? acc[r] : -3.0e38f;
      }
    } else {                        // dyadic: only diagonal entries used
      int jj = j - 80;
      int s = jj >> 4, tni = jj & 15;
      int r = tni - fq * 4;
      if (r >= 0 && r < 4) {
        bool gvalid = (n0 + tni - offsets[NDENSE + s]) >= 0;
        Sbuf[tni][NDENSE + s] = gvalid ? acc[r] : -3.0e38f;
      }
    }
  }
  __syncthreads();

  // --- Phase 2: softmax (16 threads per row), banded P -> Pd (bf16) ---
  {
    int t = tid & 15, ni = tid >> 4;
    float sc5[5];
    float m = -3.0e38f;
#pragma unroll
    for (int k = 0; k < 5; ++k) {
      int o = t + k * 16;
      float v = -3.0e38f;
      if (o < NOFF) {
        float raw = Sbuf[ni][o];
        if (raw > -1.0e38f) v = raw * 0.125f + pos_bias[o * NHEAD + h];
      }
      sc5[k] = v;
      m = fmaxf(m, v);
    }
#pragma unroll
    for (int d = 1; d < 16; d <<= 1) m = fmaxf(m, __shfl_xor(m, d));
    float sum = 0.f;
#pragma unroll
    for (int k = 0; k < 5; ++k) {
      int o = t + k * 16;
      if (o < NOFF && sc5[k] > -1.0e38f) {
        float e = __expf(sc5[k] - m);
        sum += e;
        int j = (o < NDENSE) ? (ni + 64 - o) : (80 + (o - NDENSE) * 16 + ni);
        Pd[ni * PST + j] = (__bf16)e;
      }
    }
#pragma unroll
    for (int d = 1; d < 16; d <<= 1) sum += __shfl_xor(sum, d);
    if (t == 0) inv_l[ni] = 1.f / sum;
  }
  __syncthreads();

  // --- Phase 3: PV via MFMA (each wave one 16-col d-tile) + gate epilogue ---
  {
    const int db = w;
    f32x4 acc = {};
#pragma unroll
    for (int kt = 0; kt < 7; ++kt) {
      bv8 a = *(const bv8*)(Pd + fr * PST + kt * 32 + fq * 8);
      bv8 b;
#pragma unroll
      for (int jj = 0; jj < 8; ++jj)
        b[jj] = Vbuf[(kt * 32 + fq * 8 + jj) * HDIM + db * 16 + fr];
      acc = __builtin_amdgcn_mfma_f32_16x16x32_bf16(a, b, acc, 0, 0, 0);
    }
    int d = db * 16 + fr;
#pragma unroll
    for (int r = 0; r < 4; ++r) {
      int ni = fq * 4 + r;
      float o = acc[r] * inv_l[ni];
      float gp = (float)qkv[(size_t)(n0 + ni) * LDQ + 3 * DIM + h * HDIM + d];
      float gate = 1.f / (1.f + __expf(-gp));
      fg[(size_t)(n0 + ni) * DIM + h * HDIM + d] = (__bf16)(o * gate);
    }
  }
}

// ---------------------------------------------------------------------------
extern "C" void kernel_launch(void* const* d_in, const int* in_sizes, int n_in,
                              void* d_out, int out_size, void* d_ws, size_t ws_size,
                              hipStream_t stream) {
  const float* x        = (const float*)d_in[0];
  const float* Wqkv     = (const float*)d_in[1];
  const float* bqkv     = (const float*)d_in[2];
  const float* Wgate    = (const float*)d_in[3];
  const float* bgate    = (const float*)d_in[4];
  const float* Wout     = (const float*)d_in[5];
  const float* bout     = (const float*)d_in[6];
  const float* pos_bias = (const float*)d_in[7];
  const int*   offsets  = (const int*)d_in[8];
  float* out = (float*)d_out;

  // workspace layout (bf16), cvt dst regions contiguous in this order
  __bf16* xb       = (__bf16*)d_ws;                               // 2048x1024
  __bf16* Wqkvb    = xb    + (size_t)SEQ_N * DIM;                 // 3072x1024
  __bf16* Wgateb   = Wqkvb + (size_t)3 * DIM * DIM;               // 1024x1024
  __bf16* Woutb    = Wgateb + (size_t)DIM * DIM;                  // 1024x1024
  __bf16* qkvg     = Woutb + (size_t)DIM * DIM;                   // 2048x4096
  __bf16* flatgate = qkvg + (size_t)SEQ_N * LDQ;                  // 2048x1024

  // 0) fp32 -> bf16 (single launch)
  cvt_all<<<dim3(E4 / 1024), dim3(256), 0, stream>>>(x, Wqkv, Wgate, Wout, xb);

  // 1) [qkv | gate_pre] = x @ [Wqkv;Wgate]^T + [bqkv;bgate]  -> bf16 qkvg
  gemm_bt<128, __bf16><<<dim3(LDQ / 128, SEQ_N / BM), dim3(256), 0, stream>>>(
      xb, Wqkvb, Wgateb, bqkv, bgate, 3 * DIM, qkvg, LDQ, DIM);

  // 2) attention + sigmoid-gate fuse -> flatgate (bf16)
  attn_mfma<<<dim3((SEQ_N / NT) * NHEAD), dim3(256), 0, stream>>>(
      qkvg, pos_bias, offsets, flatgate);

  // 3) out = flatgate @ Wout^T + bout  -> fp32 d_out (64x64 tiles: 512 blocks)
  gemm_bt64<float><<<dim3(DIM / 64, SEQ_N / 64), dim3(256), 0, stream>>>(
      flatgate, Woutb, bout, out, DIM, DIM);
}

// Round 10
// 144.360 us; speedup vs baseline: 1.0756x; 1.0240x over previous
//
#include <hip/hip_runtime.h>
#include <hip/hip_bf16.h>

// Problem constants (B=1, N=2048, D=1024, H=16, HD=64; NO=74 offsets)
#define SEQ_N 2048
#define DIM   1024
#define NHEAD 16
#define HDIM  64
#define LDQ   4096   // qkvg row stride: [q | k | v | gatepre]
#define NOFF  74     // 65 dense (0..64) + 9 dyadic
#define NDENSE 65
#define NJ    224    // 80 dense rows + 9*16 dyadic rows
#define NT    16     // n-rows per attention block
#define PST   232    // Pd row stride (padded, 16B-aligned)
#define QST   88     // Qbuf row stride (16B-aligned)

typedef __attribute__((ext_vector_type(8))) __bf16 bv8;
typedef __attribute__((ext_vector_type(4))) __bf16 bv4;
typedef __attribute__((ext_vector_type(4))) float  f32x4;

typedef __attribute__((address_space(3))) void as3_void;
typedef __attribute__((address_space(1))) void as1_void;

// async global->LDS 16B copy. LDS dest must be wave-uniform base + lane*16.
__device__ __forceinline__ void async16(const void* g, void* l) {
  __builtin_amdgcn_global_load_lds((as1_void*)(unsigned long long)g,
                                   (as3_void*)l, 16, 0, 0);
}

// ---------------------------------------------------------------------------
// fp32 -> bf16 convert, all 4 tensors in one launch (dst regions contiguous).
// ---------------------------------------------------------------------------
#define E1 (SEQ_N * DIM)            // x
#define E2 (E1 + 3 * DIM * DIM)     // + Wqkv
#define E3 (E2 + DIM * DIM)         // + Wgate
#define E4 (E3 + DIM * DIM)         // + Wout
__global__ __launch_bounds__(256) void cvt_all(
    const float* __restrict__ x, const float* __restrict__ wqkv,
    const float* __restrict__ wgate, const float* __restrict__ wout,
    __bf16* __restrict__ dst) {
  long i = ((long)blockIdx.x * 256 + threadIdx.x) * 4;
  if (i >= E4) return;
  const float* s; long o;
  if (i < E1)      { s = x;     o = i; }
  else if (i < E2) { s = wqkv;  o = i - E1; }
  else if (i < E3) { s = wgate; o = i - E2; }
  else             { s = wout;  o = i - E3; }
  float4 v = *(const float4*)(s + o);
  bv4 ov;
  ov[0] = (__bf16)v.x; ov[1] = (__bf16)v.y; ov[2] = (__bf16)v.z; ov[3] = (__bf16)v.w;
  *(bv4*)(dst + i) = ov;
}

// ---------------------------------------------------------------------------
// GEMM (128xBN_ tile, BKT=128): C = A[MxK] * B[NoutxK]^T + bias, bf16 in,
// fp32 accum, OutT out. B split at col Nsplit. m97 staging (async16 w=16).
// BKT=128: 8 barrier-pairs for K=1024 (64 MFMA/wave per drain). LDS 64 KB ->
// 2 blocks/CU, which equals the grid-limited residency (512 blocks/256 CU),
// so no occupancy loss (m132's BK=128 failure mode can't trigger here).
// XOR chunk-swizzle on the GLOBAL side (LDS stays contiguous for async16):
// chunk (row,qq) holds global k-chunk qq^(row&7); fragment reads use
// physical chunk (kk*4+fq)^(fr&7) -> 2-way bank aliasing only (free).
// ---------------------------------------------------------------------------
#define BM 128
#define BKT 128

template <int BN_, typename OutT>
__global__ __launch_bounds__(256) void gemm_bt(
    const __bf16* __restrict__ A, const __bf16* __restrict__ B1,
    const __bf16* __restrict__ B2, const float* __restrict__ bias1,
    const float* __restrict__ bias2, int Nsplit,
    OutT* __restrict__ C, int ldc, int K) {
  __shared__ __attribute__((aligned(16))) __bf16 Asm[BM * BKT];   // 32 KB
  __shared__ __attribute__((aligned(16))) __bf16 Bsm[BN_ * BKT];  // 32 KB
  constexpr int NJT = BN_ / 32;            // j-tiles per wave
  constexpr int CA = BM * BKT / 8;         // A 16B-chunks (2048)
  constexpr int CB = BN_ * BKT / 8;        // B 16B-chunks
  constexpr int CPR = BKT / 8;             // chunks per row (16)

  const int tid  = threadIdx.x;
  const int lane = tid & 63;
  const int wave = tid >> 6;
  const int wr = wave >> 1, wc = wave & 1;
  const int fr = lane & 15, fq = lane >> 4;
  const int fr7 = fr & 7;

  const int bn0 = blockIdx.x * BN_;
  const int bm0 = blockIdx.y * BM;

  const __bf16* Bp;
  const float* biasp;
  if (bn0 < Nsplit) { Bp = B1 + (size_t)bn0 * K;            biasp = bias1 + bn0; }
  else              { Bp = B2 + (size_t)(bn0 - Nsplit) * K; biasp = bias2 + (bn0 - Nsplit); }
  const __bf16* Ap = A + (size_t)bm0 * K;

  f32x4 acc[4][NJT] = {};

  for (int kt = 0; kt < K; kt += BKT) {
    __syncthreads();
#pragma unroll
    for (int c0 = 0; c0 < CA + CB; c0 += 256) {
      int c = c0 + tid;
      if (c < CA) {
        int rr = c / CPR, qq = c % CPR;
        int qs = qq ^ (rr & 7);
        async16(Ap + (size_t)rr * K + kt + qs * 8, Asm + c * 8);
      } else {
        int cb = c - CA;
        int rr = cb / CPR, qq = cb % CPR;
        int qs = qq ^ (rr & 7);
        async16(Bp + (size_t)rr * K + kt + qs * 8, Bsm + cb * 8);
      }
    }
    __syncthreads();

#pragma unroll
    for (int kk = 0; kk < BKT / 32; ++kk) {
      const int qs = ((kk * 4 + fq) ^ fr7) * 8;
      bv8 af[4], bfr[NJT];
#pragma unroll
      for (int i = 0; i < 4; ++i)
        af[i] = *(const bv8*)(Asm + (wr * 64 + i * 16 + fr) * BKT + qs);
#pragma unroll
      for (int j = 0; j < NJT; ++j)
        bfr[j] = *(const bv8*)(Bsm + (wc * (BN_ / 2) + j * 16 + fr) * BKT + qs);
#pragma unroll
      for (int i = 0; i < 4; ++i)
#pragma unroll
        for (int j = 0; j < NJT; ++j)
          acc[i][j] = __builtin_amdgcn_mfma_f32_16x16x32_bf16(af[i], bfr[j], acc[i][j], 0, 0, 0);
    }
  }

#pragma unroll
  for (int i = 0; i < 4; ++i) {
#pragma unroll
    for (int j = 0; j < NJT; ++j) {
      int ccol = wc * (BN_ / 2) + j * 16 + fr;
      float b = biasp[ccol];
#pragma unroll
      for (int r = 0; r < 4; ++r) {
        int row = bm0 + wr * 64 + i * 16 + fq * 4 + r;
        C[(size_t)row * ldc + bn0 + ccol] = (OutT)(acc[i][j][r] + b);
      }
    }
  }
}

// ---------------------------------------------------------------------------
// GEMM 64x64 tile, BK=64 (gemm3: 512 blocks). XOR chunk-swizzle.
// ---------------------------------------------------------------------------
#define BKG 64
template <typename OutT>
__global__ __launch_bounds__(256) void gemm_bt64(
    const __bf16* __restrict__ A, const __bf16* __restrict__ B,
    const float* __restrict__ bias, OutT* __restrict__ C, int ldc, int K) {
  __shared__ __attribute__((aligned(16))) __bf16 Asm[64 * BKG];  // 8 KB
  __shared__ __attribute__((aligned(16))) __bf16 Bsm[64 * BKG];  // 8 KB

  const int tid  = threadIdx.x;
  const int lane = tid & 63;
  const int wave = tid >> 6;
  const int wr = wave >> 1, wc = wave & 1;
  const int fr = lane & 15, fq = lane >> 4;
  const int fr7 = fr & 7;

  const int bn0 = blockIdx.x * 64;
  const int bm0 = blockIdx.y * 64;

  const __bf16* Ap = A + (size_t)bm0 * K;
  const __bf16* Bp = B + (size_t)bn0 * K;
  const float* biasp = bias + bn0;

  f32x4 acc[2][2] = {};

  for (int kt = 0; kt < K; kt += BKG) {
    __syncthreads();
#pragma unroll
    for (int c0 = 0; c0 < 512; c0 += 256) {
      int c = c0 + tid;
      int rr = c >> 3, qq = c & 7;
      int qs = qq ^ (rr & 7);
      async16(Ap + (size_t)rr * K + kt + qs * 8, Asm + c * 8);
      async16(Bp + (size_t)rr * K + kt + qs * 8, Bsm + c * 8);
    }
    __syncthreads();

#pragma unroll
    for (int kk = 0; kk < 2; ++kk) {
      const int qs = ((kk * 4 + fq) ^ fr7) * 8;
      bv8 af[2], bfr[2];
#pragma unroll
      for (int i = 0; i < 2; ++i)
        af[i] = *(const bv8*)(Asm + (wr * 32 + i * 16 + fr) * BKG + qs);
#pragma unroll
      for (int j = 0; j < 2; ++j)
        bfr[j] = *(const bv8*)(Bsm + (wc * 32 + j * 16 + fr) * BKG + qs);
#pragma unroll
      for (int i = 0; i < 2; ++i)
#pragma unroll
        for (int j = 0; j < 2; ++j)
          acc[i][j] = __builtin_amdgcn_mfma_f32_16x16x32_bf16(af[i], bfr[j], acc[i][j], 0, 0, 0);
    }
  }

#pragma unroll
  for (int i = 0; i < 2; ++i) {
#pragma unroll
    for (int j = 0; j < 2; ++j) {
      int ccol = wc * 32 + j * 16 + fr;
      float b = biasp[ccol];
#pragma unroll
      for (int r = 0; r < 4; ++r) {
        int row = bm0 + wr * 32 + i * 16 + fq * 4 + r;
        C[(size_t)row * ldc + bn0 + ccol] = (OutT)(acc[i][j][r] + b);
      }
    }
  }
}

// ---------------------------------------------------------------------------
// MFMA-tile attention + gate. One 256-thread block per (16-row n-tile, head).
// Kbuf staged with global-side XOR chunk-swizzle; Vbuf unswizzled.
// ---------------------------------------------------------------------------
__global__ __launch_bounds__(256) void attn_mfma(
    const __bf16* __restrict__ qkv,      // [SEQ_N x LDQ]
    const float* __restrict__ pos_bias,  // [NOFF x NHEAD]
    const int* __restrict__ offsets,     // [NOFF]
    __bf16* __restrict__ fg) {
  const int n0 = (blockIdx.x >> 4) * NT;
  const int h  = blockIdx.x & 15;
  const int tid = threadIdx.x;
  const int lane = tid & 63;
  const int w = tid >> 6;
  const int fr = lane & 15, fq = lane >> 4;
  const int fr7 = fr & 7;

  __shared__ __attribute__((aligned(16))) __bf16 Kbuf[NJ * HDIM];   // 28672 B
  __shared__ __attribute__((aligned(16))) __bf16 Vbuf[NJ * HDIM];   // 28672 B
  __shared__ __attribute__((aligned(16))) __bf16 Qbuf[NT * QST];    // 2816 B
  __shared__ __attribute__((aligned(16))) float  Sbuf[NT][80];      // 5120 B
  __shared__ __attribute__((aligned(16))) __bf16 Pd[NT * PST];      // 7424 B
  __shared__ float inv_l[NT];

  // --- Phase 0: stage Q, zero Pd, async-stage K (swizzled) / V (plain) ---
  if (tid < 128) {
    int ni = tid >> 3, ch = tid & 7;
    bv8 q = *(const bv8*)(qkv + (size_t)(n0 + ni) * LDQ + h * HDIM + ch * 8);
    *(bv8*)(Qbuf + ni * QST + ch * 8) = q;
  }
#pragma unroll
  for (int c0 = 0; c0 < NT * PST / 8; c0 += 256) {
    int c = c0 + tid;
    if (c < NT * PST / 8) *(uint4*)(Pd + c * 8) = make_uint4(0, 0, 0, 0);
  }
  {
    int ch = lane & 7;
    int rowin = lane >> 3;          // 0..7, equals (row index)&7
    int chs = ch ^ rowin;           // swizzled k-chunk for Kbuf
#pragma unroll
    for (int it = 0; it < 7; ++it) {
      int jbase = it * 32 + w * 8;
      int j = jbase + rowin;
      int g;
      if (j < 80) g = n0 - 64 + j;
      else { int jj = j - 80; g = n0 - offsets[NDENSE + (jj >> 4)] + (jj & 15); }
      if (g < 0) g = 0;   // clamp; masked later
      const __bf16* base = qkv + (size_t)g * LDQ + DIM + h * HDIM;
      async16(base + chs * 8, Kbuf + jbase * HDIM + lane * 8);
      async16(base + DIM + ch * 8, Vbuf + jbase * HDIM + lane * 8);
    }
  }
  __syncthreads();

  // --- Phase 1: scores via MFMA, scatter banded entries to Sbuf ---
  for (int jb = w; jb < 14; jb += 4) {
    f32x4 acc = {};
#pragma unroll
    for (int kk = 0; kk < 2; ++kk) {
      bv8 a = *(const bv8*)(Qbuf + fr * QST + kk * 32 + fq * 8);
      bv8 b = *(const bv8*)(Kbuf + (jb * 16 + fr) * HDIM + ((kk * 4 + fq) ^ fr7) * 8);
      acc = __builtin_amdgcn_mfma_f32_16x16x32_bf16(a, b, acc, 0, 0, 0);
    }
    int j = jb * 16 + fr;           // Kbuf row this lane's column maps to
    if (jb < 5) {                   // dense region
      bool gvalid = (n0 - 64 + j) >= 0;
#pragma unroll
      for (int r = 0; r < 4; ++r) {
        int ni = fq * 4 + r;
        int o = ni + 64 - j;
        if (o >= 0 && o < NDENSE)
          Sbuf[ni][o] = gvalid ? acc[r] : -3.0e38f;
      }
    } else {                        // dyadic: only diagonal entries used
      int jj = j - 80;
      int s = jj >> 4, tni = jj & 15;
      int r = tni - fq * 4;
      if (r >= 0 && r < 4) {
        bool gvalid = (n0 + tni - offsets[NDENSE + s]) >= 0;
        Sbuf[tni][NDENSE + s] = gvalid ? acc[r] : -3.0e38f;
      }
    }
  }
  __syncthreads();

  // --- Phase 2: softmax (16 threads per row), banded P -> Pd (bf16) ---
  {
    int t = tid & 15, ni = tid >> 4;
    float sc5[5];
    float m = -3.0e38f;
#pragma unroll
    for (int k = 0; k < 5; ++k) {
      int o = t + k * 16;
      float v = -3.0e38f;
      if (o < NOFF) {
        float raw = Sbuf[ni][o];
        if (raw > -1.0e38f) v = raw * 0.125f + pos_bias[o * NHEAD + h];
      }
      sc5[k] = v;
      m = fmaxf(m, v);
    }
#pragma unroll
    for (int d = 1; d < 16; d <<= 1) m = fmaxf(m, __shfl_xor(m, d));
    float sum = 0.f;
#pragma unroll
    for (int k = 0; k < 5; ++k) {
      int o = t + k * 16;
      if (o < NOFF && sc5[k] > -1.0e38f) {
        float e = __expf(sc5[k] - m);
        sum += e;
        int j = (o < NDENSE) ? (ni + 64 - o) : (80 + (o - NDENSE) * 16 + ni);
        Pd[ni * PST + j] = (__bf16)e;
      }
    }
#pragma unroll
    for (int d = 1; d < 16; d <<= 1) sum += __shfl_xor(sum, d);
    if (t == 0) inv_l[ni] = 1.f / sum;
  }
  __syncthreads();

  // --- Phase 3: PV via MFMA (each wave one 16-col d-tile) + gate epilogue ---
  {
    const int db = w;
    f32x4 acc = {};
#pragma unroll
    for (int kt = 0; kt < 7; ++kt) {
      bv8 a = *(const bv8*)(Pd + fr * PST + kt * 32 + fq * 8);
      bv8 b;
#pragma unroll
      for (int jj = 0; jj < 8; ++jj)
        b[jj] = Vbuf[(kt * 32 + fq * 8 + jj) * HDIM + db * 16 + fr];
      acc = __builtin_amdgcn_mfma_f32_16x16x32_bf16(a, b, acc, 0, 0, 0);
    }
    int d = db * 16 + fr;
#pragma unroll
    for (int r = 0; r < 4; ++r) {
      int ni = fq * 4 + r;
      float o = acc[r] * inv_l[ni];
      float gp = (float)qkv[(size_t)(n0 + ni) * LDQ + 3 * DIM + h * HDIM + d];
      float gate = 1.f / (1.f + __expf(-gp));
      fg[(size_t)(n0 + ni) * DIM + h * HDIM + d] = (__bf16)(o * gate);
    }
  }
}

// ---------------------------------------------------------------------------
extern "C" void kernel_launch(void* const* d_in, const int* in_sizes, int n_in,
                              void* d_out, int out_size, void* d_ws, size_t ws_size,
                              hipStream_t stream) {
  const float* x        = (const float*)d_in[0];
  const float* Wqkv     = (const float*)d_in[1];
  const float* bqkv     = (const float*)d_in[2];
  const float* Wgate    = (const float*)d_in[3];
  const float* bgate    = (const float*)d_in[4];
  const float* Wout     = (const float*)d_in[5];
  const float* bout     = (const float*)d_in[6];
  const float* pos_bias = (const float*)d_in[7];
  const int*   offsets  = (const int*)d_in[8];
  float* out = (float*)d_out;

  // workspace layout (bf16), cvt dst regions contiguous in this order
  __bf16* xb       = (__bf16*)d_ws;                               // 2048x1024
  __bf16* Wqkvb    = xb    + (size_t)SEQ_N * DIM;                 // 3072x1024
  __bf16* Wgateb   = Wqkvb + (size_t)3 * DIM * DIM;               // 1024x1024
  __bf16* Woutb    = Wgateb + (size_t)DIM * DIM;                  // 1024x1024
  __bf16* qkvg     = Woutb + (size_t)DIM * DIM;                   // 2048x4096
  __bf16* flatgate = qkvg + (size_t)SEQ_N * LDQ;                  // 2048x1024

  // 0) fp32 -> bf16 (single launch)
  cvt_all<<<dim3(E4 / 1024), dim3(256), 0, stream>>>(x, Wqkv, Wgate, Wout, xb);

  // 1) [qkv | gate_pre] = x @ [Wqkv;Wgate]^T + [bqkv;bgate]  -> bf16 qkvg
  gemm_bt<128, __bf16><<<dim3(LDQ / 128, SEQ_N / BM), dim3(256), 0, stream>>>(
      xb, Wqkvb, Wgateb, bqkv, bgate, 3 * DIM, qkvg, LDQ, DIM);

  // 2) attention + sigmoid-gate fuse -> flatgate (bf16)
  attn_mfma<<<dim3((SEQ_N / NT) * NHEAD), dim3(256), 0, stream>>>(
      qkvg, pos_bias, offsets, flatgate);

  // 3) out = flatgate @ Wout^T + bout  -> fp32 d_out (64x64 tiles: 512 blocks)
  gemm_bt64<float><<<dim3(DIM / 64, SEQ_N / 64), dim3(256), 0, stream>>>(
      flatgate, Woutb, bout, out, DIM, DIM);
}

// Round 11
// 141.066 us; speedup vs baseline: 1.1007x; 1.0233x over previous
//
#include <hip/hip_runtime.h>
#include <hip/hip_bf16.h>

// Problem constants (B=1, N=2048, D=1024, H=16, HD=64; NO=74 offsets)
#define SEQ_N 2048
#define DIM   1024
#define NHEAD 16
#define HDIM  64
#define LDQ   4096   // qkvg row stride: [q | k | v | gatepre]
#define NOFF  74     // 65 dense (0..64) + 9 dyadic
#define NDENSE 65
#define NJ    224    // 80 dense rows + 9*16 dyadic rows
#define NT    16     // n-rows per attention block
#define PST   232    // Pd row stride (padded, 16B-aligned)
#define QST   88     // Qbuf row stride (16B-aligned)

typedef __attribute__((ext_vector_type(8))) __bf16 bv8;
typedef __attribute__((ext_vector_type(4))) __bf16 bv4;
typedef __attribute__((ext_vector_type(4))) float  f32x4;

typedef __attribute__((address_space(3))) void as3_void;
typedef __attribute__((address_space(1))) void as1_void;

// async global->LDS 16B copy. LDS dest must be wave-uniform base + lane*16.
__device__ __forceinline__ void async16(const void* g, void* l) {
  __builtin_amdgcn_global_load_lds((as1_void*)(unsigned long long)g,
                                   (as3_void*)l, 16, 0, 0);
}

// ---------------------------------------------------------------------------
// fp32 -> bf16 convert, all 4 tensors in one launch (dst regions contiguous).
// ---------------------------------------------------------------------------
#define E1 (SEQ_N * DIM)            // x
#define E2 (E1 + 3 * DIM * DIM)     // + Wqkv
#define E3 (E2 + DIM * DIM)         // + Wgate
#define E4 (E3 + DIM * DIM)         // + Wout
__global__ __launch_bounds__(256) void cvt_all(
    const float* __restrict__ x, const float* __restrict__ wqkv,
    const float* __restrict__ wgate, const float* __restrict__ wout,
    __bf16* __restrict__ dst) {
  long i = ((long)blockIdx.x * 256 + threadIdx.x) * 4;
  if (i >= E4) return;
  const float* s; long o;
  if (i < E1)      { s = x;     o = i; }
  else if (i < E2) { s = wqkv;  o = i - E1; }
  else if (i < E3) { s = wgate; o = i - E2; }
  else             { s = wout;  o = i - E3; }
  float4 v = *(const float4*)(s + o);
  bv4 ov;
  ov[0] = (__bf16)v.x; ov[1] = (__bf16)v.y; ov[2] = (__bf16)v.z; ov[3] = (__bf16)v.w;
  *(bv4*)(dst + i) = ov;
}

// ---------------------------------------------------------------------------
// GEMM (128xBN_ tile, BKT=128): C = A[MxK] * B[NoutxK]^T + bias, bf16 in,
// fp32 accum, OutT out. B split at col Nsplit. m97 staging (async16 w=16).
// 8 barrier-pairs for K=1024. LDS 64 KB -> 2 blocks/CU = grid-limited
// residency. Global-side XOR chunk-swizzle (R9 win: conflicts 6.3M -> ~0).
// ---------------------------------------------------------------------------
#define BM 128
#define BKT 128

template <int BN_, typename OutT>
__global__ __launch_bounds__(256) void gemm_bt(
    const __bf16* __restrict__ A, const __bf16* __restrict__ B1,
    const __bf16* __restrict__ B2, const float* __restrict__ bias1,
    const float* __restrict__ bias2, int Nsplit,
    OutT* __restrict__ C, int ldc, int K) {
  __shared__ __attribute__((aligned(16))) __bf16 Asm[BM * BKT];   // 32 KB
  __shared__ __attribute__((aligned(16))) __bf16 Bsm[BN_ * BKT];  // 32 KB
  constexpr int NJT = BN_ / 32;
  constexpr int CA = BM * BKT / 8;
  constexpr int CB = BN_ * BKT / 8;
  constexpr int CPR = BKT / 8;             // 16

  const int tid  = threadIdx.x;
  const int lane = tid & 63;
  const int wave = tid >> 6;
  const int wr = wave >> 1, wc = wave & 1;
  const int fr = lane & 15, fq = lane >> 4;
  const int fr7 = fr & 7;

  const int bn0 = blockIdx.x * BN_;
  const int bm0 = blockIdx.y * BM;

  const __bf16* Bp;
  const float* biasp;
  if (bn0 < Nsplit) { Bp = B1 + (size_t)bn0 * K;            biasp = bias1 + bn0; }
  else              { Bp = B2 + (size_t)(bn0 - Nsplit) * K; biasp = bias2 + (bn0 - Nsplit); }
  const __bf16* Ap = A + (size_t)bm0 * K;

  f32x4 acc[4][NJT] = {};

  for (int kt = 0; kt < K; kt += BKT) {
    __syncthreads();
#pragma unroll
    for (int c0 = 0; c0 < CA + CB; c0 += 256) {
      int c = c0 + tid;
      if (c < CA) {
        int rr = c / CPR, qq = c % CPR;
        int qs = qq ^ (rr & 7);
        async16(Ap + (size_t)rr * K + kt + qs * 8, Asm + c * 8);
      } else {
        int cb = c - CA;
        int rr = cb / CPR, qq = cb % CPR;
        int qs = qq ^ (rr & 7);
        async16(Bp + (size_t)rr * K + kt + qs * 8, Bsm + cb * 8);
      }
    }
    __syncthreads();

#pragma unroll
    for (int kk = 0; kk < BKT / 32; ++kk) {
      const int qs = ((kk * 4 + fq) ^ fr7) * 8;
      bv8 af[4], bfr[NJT];
#pragma unroll
      for (int i = 0; i < 4; ++i)
        af[i] = *(const bv8*)(Asm + (wr * 64 + i * 16 + fr) * BKT + qs);
#pragma unroll
      for (int j = 0; j < NJT; ++j)
        bfr[j] = *(const bv8*)(Bsm + (wc * (BN_ / 2) + j * 16 + fr) * BKT + qs);
#pragma unroll
      for (int i = 0; i < 4; ++i)
#pragma unroll
        for (int j = 0; j < NJT; ++j)
          acc[i][j] = __builtin_amdgcn_mfma_f32_16x16x32_bf16(af[i], bfr[j], acc[i][j], 0, 0, 0);
    }
  }

#pragma unroll
  for (int i = 0; i < 4; ++i) {
#pragma unroll
    for (int j = 0; j < NJT; ++j) {
      int ccol = wc * (BN_ / 2) + j * 16 + fr;
      float b = biasp[ccol];
#pragma unroll
      for (int r = 0; r < 4; ++r) {
        int row = bm0 + wr * 64 + i * 16 + fq * 4 + r;
        C[(size_t)row * ldc + bn0 + ccol] = (OutT)(acc[i][j][r] + b);
      }
    }
  }
}

// ---------------------------------------------------------------------------
// GEMM 64x64 tile, BKT=128 (gemm3: 512 blocks = 2/CU grid-limited; LDS 32 KB
// allows 5 -> no occupancy loss; barrier pairs 16 -> 8). XOR chunk-swizzle.
// ---------------------------------------------------------------------------
template <typename OutT>
__global__ __launch_bounds__(256) void gemm_bt64(
    const __bf16* __restrict__ A, const __bf16* __restrict__ B,
    const float* __restrict__ bias, OutT* __restrict__ C, int ldc, int K) {
  __shared__ __attribute__((aligned(16))) __bf16 Asm[64 * BKT];  // 16 KB
  __shared__ __attribute__((aligned(16))) __bf16 Bsm[64 * BKT];  // 16 KB
  constexpr int CM = 64 * BKT / 8;         // 1024 chunks per matrix
  constexpr int CPR = BKT / 8;             // 16

  const int tid  = threadIdx.x;
  const int lane = tid & 63;
  const int wave = tid >> 6;
  const int wr = wave >> 1, wc = wave & 1;
  const int fr = lane & 15, fq = lane >> 4;
  const int fr7 = fr & 7;

  const int bn0 = blockIdx.x * 64;
  const int bm0 = blockIdx.y * 64;

  const __bf16* Ap = A + (size_t)bm0 * K;
  const __bf16* Bp = B + (size_t)bn0 * K;
  const float* biasp = bias + bn0;

  f32x4 acc[2][2] = {};

  for (int kt = 0; kt < K; kt += BKT) {
    __syncthreads();
#pragma unroll
    for (int c0 = 0; c0 < CM; c0 += 256) {
      int c = c0 + tid;
      int rr = c / CPR, qq = c % CPR;
      int qs = qq ^ (rr & 7);
      async16(Ap + (size_t)rr * K + kt + qs * 8, Asm + c * 8);
      async16(Bp + (size_t)rr * K + kt + qs * 8, Bsm + c * 8);
    }
    __syncthreads();

#pragma unroll
    for (int kk = 0; kk < BKT / 32; ++kk) {
      const int qs = ((kk * 4 + fq) ^ fr7) * 8;
      bv8 af[2], bfr[2];
#pragma unroll
      for (int i = 0; i < 2; ++i)
        af[i] = *(const bv8*)(Asm + (wr * 32 + i * 16 + fr) * BKT + qs);
#pragma unroll
      for (int j = 0; j < 2; ++j)
        bfr[j] = *(const bv8*)(Bsm + (wc * 32 + j * 16 + fr) * BKT + qs);
#pragma unroll
      for (int i = 0; i < 2; ++i)
#pragma unroll
        for (int j = 0; j < 2; ++j)
          acc[i][j] = __builtin_amdgcn_mfma_f32_16x16x32_bf16(af[i], bfr[j], acc[i][j], 0, 0, 0);
    }
  }

#pragma unroll
  for (int i = 0; i < 2; ++i) {
#pragma unroll
    for (int j = 0; j < 2; ++j) {
      int ccol = wc * 32 + j * 16 + fr;
      float b = biasp[ccol];
#pragma unroll
      for (int r = 0; r < 4; ++r) {
        int row = bm0 + wr * 32 + i * 16 + fq * 4 + r;
        C[(size_t)row * ldc + bn0 + ccol] = (OutT)(acc[i][j][r] + b);
      }
    }
  }
}

// ---------------------------------------------------------------------------
// MFMA-tile attention + gate. One 256-thread block per (16-row n-tile, head).
// SINGLE K/V buffer (K dead after Phase 1): Phase 0 stages K (swizzled);
// after the Phase-1 barrier, V async16s are issued into the same buffer and
// fly during Phase-2 softmax (touches only Sbuf/Pd); the pre-Phase-3
// __syncthreads vmcnt(0) drain publishes V. LDS 44.1 KB -> 3 blocks/CU.
// ---------------------------------------------------------------------------
__global__ __launch_bounds__(256) void attn_mfma(
    const __bf16* __restrict__ qkv,      // [SEQ_N x LDQ]
    const float* __restrict__ pos_bias,  // [NOFF x NHEAD]
    const int* __restrict__ offsets,     // [NOFF]
    __bf16* __restrict__ fg) {
  const int n0 = (blockIdx.x >> 4) * NT;
  const int h  = blockIdx.x & 15;
  const int tid = threadIdx.x;
  const int lane = tid & 63;
  const int w = tid >> 6;
  const int fr = lane & 15, fq = lane >> 4;
  const int fr7 = fr & 7;

  __shared__ __attribute__((aligned(16))) __bf16 KVbuf[NJ * HDIM];  // 28672 B
  __shared__ __attribute__((aligned(16))) __bf16 Qbuf[NT * QST];    // 2816 B
  __shared__ __attribute__((aligned(16))) float  Sbuf[NT][80];      // 5120 B
  __shared__ __attribute__((aligned(16))) __bf16 Pd[NT * PST];      // 7424 B
  __shared__ float inv_l[NT];

  const int ch = lane & 7;
  const int rowin = lane >> 3;          // 0..7, equals (row index)&7

  // --- Phase 0: stage Q, zero Pd, async-stage K (swizzled chunks) ---
  if (tid < 128) {
    int ni = tid >> 3, cq = tid & 7;
    bv8 q = *(const bv8*)(qkv + (size_t)(n0 + ni) * LDQ + h * HDIM + cq * 8);
    *(bv8*)(Qbuf + ni * QST + cq * 8) = q;
  }
#pragma unroll
  for (int c0 = 0; c0 < NT * PST / 8; c0 += 256) {
    int c = c0 + tid;
    if (c < NT * PST / 8) *(uint4*)(Pd + c * 8) = make_uint4(0, 0, 0, 0);
  }
  {
    int chs = ch ^ rowin;           // swizzled k-chunk for K staging
#pragma unroll
    for (int it = 0; it < 7; ++it) {
      int jbase = it * 32 + w * 8;
      int j = jbase + rowin;
      int g;
      if (j < 80) g = n0 - 64 + j;
      else { int jj = j - 80; g = n0 - offsets[NDENSE + (jj >> 4)] + (jj & 15); }
      if (g < 0) g = 0;   // clamp; masked later
      async16(qkv + (size_t)g * LDQ + DIM + h * HDIM + chs * 8,
              KVbuf + jbase * HDIM + lane * 8);
    }
  }
  __syncthreads();

  // --- Phase 1: scores via MFMA, scatter banded entries to Sbuf ---
  for (int jb = w; jb < 14; jb += 4) {
    f32x4 acc = {};
#pragma unroll
    for (int kk = 0; kk < 2; ++kk) {
      bv8 a = *(const bv8*)(Qbuf + fr * QST + kk * 32 + fq * 8);
      bv8 b = *(const bv8*)(KVbuf + (jb * 16 + fr) * HDIM + ((kk * 4 + fq) ^ fr7) * 8);
      acc = __builtin_amdgcn_mfma_f32_16x16x32_bf16(a, b, acc, 0, 0, 0);
    }
    int j = jb * 16 + fr;           // K row this lane's column maps to
    if (jb < 5) {                   // dense region
      bool gvalid = (n0 - 64 + j) >= 0;
#pragma unroll
      for (int r = 0; r < 4; ++r) {
        int ni = fq * 4 + r;
        int o = ni + 64 - j;
        if (o >= 0 && o < NDENSE)
          Sbuf[ni][o] = gvalid ? acc[r] : -3.0e38f;
      }
    } else {                        // dyadic: only diagonal entries used
      int jj = j - 80;
      int s = jj >> 4, tni = jj & 15;
      int r = tni - fq * 4;
      if (r >= 0 && r < 4) {
        bool gvalid = (n0 + tni - offsets[NDENSE + s]) >= 0;
        Sbuf[tni][NDENSE + s] = gvalid ? acc[r] : -3.0e38f;
      }
    }
  }
  __syncthreads();   // all K reads done -> KVbuf reusable; Sbuf published

  // --- stage V into KVbuf (plain chunks); overlaps Phase-2 softmax ---
#pragma unroll
  for (int it = 0; it < 7; ++it) {
    int jbase = it * 32 + w * 8;
    int j = jbase + rowin;
    int g;
    if (j < 80) g = n0 - 64 + j;
    else { int jj = j - 80; g = n0 - offsets[NDENSE + (jj >> 4)] + (jj & 15); }
    if (g < 0) g = 0;
    async16(qkv + (size_t)g * LDQ + 2 * DIM + h * HDIM + ch * 8,
            KVbuf + jbase * HDIM + lane * 8);
  }

  // --- Phase 2: softmax (16 threads per row), banded P -> Pd (bf16) ---
  {
    int t = tid & 15, ni = tid >> 4;
    float sc5[5];
    float m = -3.0e38f;
#pragma unroll
    for (int k = 0; k < 5; ++k) {
      int o = t + k * 16;
      float v = -3.0e38f;
      if (o < NOFF) {
        float raw = Sbuf[ni][o];
        if (raw > -1.0e38f) v = raw * 0.125f + pos_bias[o * NHEAD + h];
      }
      sc5[k] = v;
      m = fmaxf(m, v);
    }
#pragma unroll
    for (int d = 1; d < 16; d <<= 1) m = fmaxf(m, __shfl_xor(m, d));
    float sum = 0.f;
#pragma unroll
    for (int k = 0; k < 5; ++k) {
      int o = t + k * 16;
      if (o < NOFF && sc5[k] > -1.0e38f) {
        float e = __expf(sc5[k] - m);
        sum += e;
        int j = (o < NDENSE) ? (ni + 64 - o) : (80 + (o - NDENSE) * 16 + ni);
        Pd[ni * PST + j] = (__bf16)e;
      }
    }
#pragma unroll
    for (int d = 1; d < 16; d <<= 1) sum += __shfl_xor(sum, d);
    if (t == 0) inv_l[ni] = 1.f / sum;
  }
  __syncthreads();   // drains V async16s (vmcnt 0) + publishes Pd/inv_l

  // --- Phase 3: PV via MFMA (each wave one 16-col d-tile) + gate epilogue ---
  {
    const int db = w;
    f32x4 acc = {};
#pragma unroll
    for (int kt = 0; kt < 7; ++kt) {
      bv8 a = *(const bv8*)(Pd + fr * PST + kt * 32 + fq * 8);
      bv8 b;
#pragma unroll
      for (int jj = 0; jj < 8; ++jj)
        b[jj] = KVbuf[(kt * 32 + fq * 8 + jj) * HDIM + db * 16 + fr];
      acc = __builtin_amdgcn_mfma_f32_16x16x32_bf16(a, b, acc, 0, 0, 0);
    }
    int d = db * 16 + fr;
#pragma unroll
    for (int r = 0; r < 4; ++r) {
      int ni = fq * 4 + r;
      float o = acc[r] * inv_l[ni];
      float gp = (float)qkv[(size_t)(n0 + ni) * LDQ + 3 * DIM + h * HDIM + d];
      float gate = 1.f / (1.f + __expf(-gp));
      fg[(size_t)(n0 + ni) * DIM + h * HDIM + d] = (__bf16)(o * gate);
    }
  }
}

// ---------------------------------------------------------------------------
extern "C" void kernel_launch(void* const* d_in, const int* in_sizes, int n_in,
                              void* d_out, int out_size, void* d_ws, size_t ws_size,
                              hipStream_t stream) {
  const float* x        = (const float*)d_in[0];
  const float* Wqkv     = (const float*)d_in[1];
  const float* bqkv     = (const float*)d_in[2];
  const float* Wgate    = (const float*)d_in[3];
  const float* bgate    = (const float*)d_in[4];
  const float* Wout     = (const float*)d_in[5];
  const float* bout     = (const float*)d_in[6];
  const float* pos_bias = (const float*)d_in[7];
  const int*   offsets  = (const int*)d_in[8];
  float* out = (float*)d_out;

  // workspace layout (bf16), cvt dst regions contiguous in this order
  __bf16* xb       = (__bf16*)d_ws;                               // 2048x1024
  __bf16* Wqkvb    = xb    + (size_t)SEQ_N * DIM;                 // 3072x1024
  __bf16* Wgateb   = Wqkvb + (size_t)3 * DIM * DIM;               // 1024x1024
  __bf16* Woutb    = Wgateb + (size_t)DIM * DIM;                  // 1024x1024
  __bf16* qkvg     = Woutb + (size_t)DIM * DIM;                   // 2048x4096
  __bf16* flatgate = qkvg + (size_t)SEQ_N * LDQ;                  // 2048x1024

  // 0) fp32 -> bf16 (single launch)
  cvt_all<<<dim3(E4 / 1024), dim3(256), 0, stream>>>(x, Wqkv, Wgate, Wout, xb);

  // 1) [qkv | gate_pre] = x @ [Wqkv;Wgate]^T + [bqkv;bgate]  -> bf16 qkvg
  gemm_bt<128, __bf16><<<dim3(LDQ / 128, SEQ_N / BM), dim3(256), 0, stream>>>(
      xb, Wqkvb, Wgateb, bqkv, bgate, 3 * DIM, qkvg, LDQ, DIM);

  // 2) attention + sigmoid-gate fuse -> flatgate (bf16)
  attn_mfma<<<dim3((SEQ_N / NT) * NHEAD), dim3(256), 0, stream>>>(
      qkvg, pos_bias, offsets, flatgate);

  // 3) out = flatgate @ Wout^T + bout  -> fp32 d_out (64x64 tiles: 512 blocks)
  gemm_bt64<float><<<dim3(DIM / 64, SEQ_N / 64), dim3(256), 0, stream>>>(
      flatgate, Woutb, bout, out, DIM, DIM);
}

// Round 12
// 140.798 us; speedup vs baseline: 1.1028x; 1.0019x over previous
//
#include <hip/hip_runtime.h>
#include <hip/hip_bf16.h>

// Problem constants (B=1, N=2048, D=1024, H=16, HD=64; NO=74 offsets)
#define SEQ_N 2048
#define DIM   1024
#define NHEAD 16
#define HDIM  64
#define LDQ   4096   // qkvg row stride: [q | k | v | gatepre]
#define NOFF  74     // 65 dense (0..64) + 9 dyadic
#define NDENSE 65
#define NJ    224    // 80 dense rows + 9*16 dyadic rows
#define NT    16     // n-rows per attention block
#define PST   232    // Pd row stride (padded, 16B-aligned)
#define QST   88     // Qbuf row stride (16B-aligned)

typedef __attribute__((ext_vector_type(8)))  __bf16 bv8;
typedef __attribute__((ext_vector_type(4)))  __bf16 bv4;
typedef __attribute__((ext_vector_type(4)))  float  f32x4;
typedef __attribute__((ext_vector_type(16))) float  f32x16;

typedef __attribute__((address_space(3))) void as3_void;
typedef __attribute__((address_space(1))) void as1_void;

// async global->LDS 16B copy. LDS dest must be wave-uniform base + lane*16.
__device__ __forceinline__ void async16(const void* g, void* l) {
  __builtin_amdgcn_global_load_lds((as1_void*)(unsigned long long)g,
                                   (as3_void*)l, 16, 0, 0);
}

// ---------------------------------------------------------------------------
// fp32 -> bf16 convert, all 4 tensors in one launch (dst regions contiguous).
// ---------------------------------------------------------------------------
#define E1 (SEQ_N * DIM)            // x
#define E2 (E1 + 3 * DIM * DIM)     // + Wqkv
#define E3 (E2 + DIM * DIM)         // + Wgate
#define E4 (E3 + DIM * DIM)         // + Wout
__global__ __launch_bounds__(256) void cvt_all(
    const float* __restrict__ x, const float* __restrict__ wqkv,
    const float* __restrict__ wgate, const float* __restrict__ wout,
    __bf16* __restrict__ dst) {
  long i = ((long)blockIdx.x * 256 + threadIdx.x) * 4;
  if (i >= E4) return;
  const float* s; long o;
  if (i < E1)      { s = x;     o = i; }
  else if (i < E2) { s = wqkv;  o = i - E1; }
  else if (i < E3) { s = wgate; o = i - E2; }
  else             { s = wout;  o = i - E3; }
  float4 v = *(const float4*)(s + o);
  bv4 ov;
  ov[0] = (__bf16)v.x; ov[1] = (__bf16)v.y; ov[2] = (__bf16)v.z; ov[3] = (__bf16)v.w;
  *(bv4*)(dst + i) = ov;
}

// ---------------------------------------------------------------------------
// GEMM (128xBN_ tile, BKT=128): C = A[MxK] * B[NoutxK]^T + bias, bf16 in,
// fp32 accum, OutT out. B split at col Nsplit. m97 staging (async16 w=16),
// global-side XOR chunk-swizzle (R9). Inner compute: v_mfma_f32_32x32x16_bf16
// (R12: ~15% faster MFMA pipe at identical ds_read count; A/B layout
// m=lane&31, k=8*(lane>>5)+i; C/D col=lane&31,
// row=(reg&3)+8*(reg>>2)+4*(lane>>5) [m74/m101 verified]).
// ---------------------------------------------------------------------------
#define BM 128
#define BKT 128

template <int BN_, typename OutT>
__global__ __launch_bounds__(256) void gemm_bt(
    const __bf16* __restrict__ A, const __bf16* __restrict__ B1,
    const __bf16* __restrict__ B2, const float* __restrict__ bias1,
    const float* __restrict__ bias2, int Nsplit,
    OutT* __restrict__ C, int ldc, int K) {
  __shared__ __attribute__((aligned(16))) __bf16 Asm[BM * BKT];   // 32 KB
  __shared__ __attribute__((aligned(16))) __bf16 Bsm[BN_ * BKT];  // 32 KB
  constexpr int NJ32 = BN_ / 64;           // 32-col j-tiles per wave
  constexpr int CA = BM * BKT / 8;
  constexpr int CB = BN_ * BKT / 8;
  constexpr int CPR = BKT / 8;             // 16

  const int tid  = threadIdx.x;
  const int lane = tid & 63;
  const int wave = tid >> 6;
  const int wr = wave >> 1, wc = wave & 1;
  const int m31 = lane & 31;               // MFMA row/col within 32-tile
  const int h1  = lane >> 5;               // k-half selector
  const int l7  = lane & 7;                // swizzle key (= row&7)

  const int bn0 = blockIdx.x * BN_;
  const int bm0 = blockIdx.y * BM;

  const __bf16* Bp;
  const float* biasp;
  if (bn0 < Nsplit) { Bp = B1 + (size_t)bn0 * K;            biasp = bias1 + bn0; }
  else              { Bp = B2 + (size_t)(bn0 - Nsplit) * K; biasp = bias2 + (bn0 - Nsplit); }
  const __bf16* Ap = A + (size_t)bm0 * K;

  f32x16 acc[2][NJ32] = {};

  for (int kt = 0; kt < K; kt += BKT) {
    __syncthreads();
#pragma unroll
    for (int c0 = 0; c0 < CA + CB; c0 += 256) {
      int c = c0 + tid;
      if (c < CA) {
        int rr = c / CPR, qq = c % CPR;
        int qs = qq ^ (rr & 7);
        async16(Ap + (size_t)rr * K + kt + qs * 8, Asm + c * 8);
      } else {
        int cb = c - CA;
        int rr = cb / CPR, qq = cb % CPR;
        int qs = qq ^ (rr & 7);
        async16(Bp + (size_t)rr * K + kt + qs * 8, Bsm + cb * 8);
      }
    }
    __syncthreads();

#pragma unroll
    for (int kk = 0; kk < BKT / 16; ++kk) {
      const int qs = ((kk * 2 + h1) ^ l7) * 8;
      bv8 af[2], bfr[NJ32];
#pragma unroll
      for (int i = 0; i < 2; ++i)
        af[i] = *(const bv8*)(Asm + (wr * 64 + i * 32 + m31) * BKT + qs);
#pragma unroll
      for (int j = 0; j < NJ32; ++j)
        bfr[j] = *(const bv8*)(Bsm + (wc * (BN_ / 2) + j * 32 + m31) * BKT + qs);
#pragma unroll
      for (int i = 0; i < 2; ++i)
#pragma unroll
        for (int j = 0; j < NJ32; ++j)
          acc[i][j] = __builtin_amdgcn_mfma_f32_32x32x16_bf16(af[i], bfr[j], acc[i][j], 0, 0, 0);
    }
  }

#pragma unroll
  for (int i = 0; i < 2; ++i) {
#pragma unroll
    for (int j = 0; j < NJ32; ++j) {
      int ccol = wc * (BN_ / 2) + j * 32 + m31;
      float b = biasp[ccol];
#pragma unroll
      for (int reg = 0; reg < 16; ++reg) {
        int row = bm0 + wr * 64 + i * 32 + (reg & 3) + 8 * (reg >> 2) + 4 * h1;
        C[(size_t)row * ldc + bn0 + ccol] = (OutT)(acc[i][j][reg] + b);
      }
    }
  }
}

// ---------------------------------------------------------------------------
// GEMM 64x64 tile, BKT=128 (gemm3). Same 32x32x16 MFMA + XOR chunk-swizzle.
// Each wave: one 32x32 tile, one chained accumulator.
// ---------------------------------------------------------------------------
template <typename OutT>
__global__ __launch_bounds__(256) void gemm_bt64(
    const __bf16* __restrict__ A, const __bf16* __restrict__ B,
    const float* __restrict__ bias, OutT* __restrict__ C, int ldc, int K) {
  __shared__ __attribute__((aligned(16))) __bf16 Asm[64 * BKT];  // 16 KB
  __shared__ __attribute__((aligned(16))) __bf16 Bsm[64 * BKT];  // 16 KB
  constexpr int CM = 64 * BKT / 8;         // 1024 chunks per matrix
  constexpr int CPR = BKT / 8;             // 16

  const int tid  = threadIdx.x;
  const int lane = tid & 63;
  const int wave = tid >> 6;
  const int wr = wave >> 1, wc = wave & 1;
  const int m31 = lane & 31;
  const int h1  = lane >> 5;
  const int l7  = lane & 7;

  const int bn0 = blockIdx.x * 64;
  const int bm0 = blockIdx.y * 64;

  const __bf16* Ap = A + (size_t)bm0 * K;
  const __bf16* Bp = B + (size_t)bn0 * K;
  const float* biasp = bias + bn0;

  f32x16 acc = {};

  for (int kt = 0; kt < K; kt += BKT) {
    __syncthreads();
#pragma unroll
    for (int c0 = 0; c0 < CM; c0 += 256) {
      int c = c0 + tid;
      int rr = c / CPR, qq = c % CPR;
      int qs = qq ^ (rr & 7);
      async16(Ap + (size_t)rr * K + kt + qs * 8, Asm + c * 8);
      async16(Bp + (size_t)rr * K + kt + qs * 8, Bsm + c * 8);
    }
    __syncthreads();

#pragma unroll
    for (int kk = 0; kk < BKT / 16; ++kk) {
      const int qs = ((kk * 2 + h1) ^ l7) * 8;
      bv8 a = *(const bv8*)(Asm + (wr * 32 + m31) * BKT + qs);
      bv8 b = *(const bv8*)(Bsm + (wc * 32 + m31) * BKT + qs);
      acc = __builtin_amdgcn_mfma_f32_32x32x16_bf16(a, b, acc, 0, 0, 0);
    }
  }

  {
    int ccol = wc * 32 + m31;
    float b = biasp[ccol];
#pragma unroll
    for (int reg = 0; reg < 16; ++reg) {
      int row = bm0 + wr * 32 + (reg & 3) + 8 * (reg >> 2) + 4 * h1;
      C[(size_t)row * ldc + bn0 + ccol] = (OutT)(acc[reg] + b);
    }
  }
}

// ---------------------------------------------------------------------------
// MFMA-tile attention + gate (R11 version: single K/V buffer, V staged
// during softmax; 44.1 KB LDS -> 3 blocks/CU). Unchanged this round.
// ---------------------------------------------------------------------------
__global__ __launch_bounds__(256) void attn_mfma(
    const __bf16* __restrict__ qkv,      // [SEQ_N x LDQ]
    const float* __restrict__ pos_bias,  // [NOFF x NHEAD]
    const int* __restrict__ offsets,     // [NOFF]
    __bf16* __restrict__ fg) {
  const int n0 = (blockIdx.x >> 4) * NT;
  const int h  = blockIdx.x & 15;
  const int tid = threadIdx.x;
  const int lane = tid & 63;
  const int w = tid >> 6;
  const int fr = lane & 15, fq = lane >> 4;
  const int fr7 = fr & 7;

  __shared__ __attribute__((aligned(16))) __bf16 KVbuf[NJ * HDIM];  // 28672 B
  __shared__ __attribute__((aligned(16))) __bf16 Qbuf[NT * QST];    // 2816 B
  __shared__ __attribute__((aligned(16))) float  Sbuf[NT][80];      // 5120 B
  __shared__ __attribute__((aligned(16))) __bf16 Pd[NT * PST];      // 7424 B
  __shared__ float inv_l[NT];

  const int ch = lane & 7;
  const int rowin = lane >> 3;          // 0..7, equals (row index)&7

  // --- Phase 0: stage Q, zero Pd, async-stage K (swizzled chunks) ---
  if (tid < 128) {
    int ni = tid >> 3, cq = tid & 7;
    bv8 q = *(const bv8*)(qkv + (size_t)(n0 + ni) * LDQ + h * HDIM + cq * 8);
    *(bv8*)(Qbuf + ni * QST + cq * 8) = q;
  }
#pragma unroll
  for (int c0 = 0; c0 < NT * PST / 8; c0 += 256) {
    int c = c0 + tid;
    if (c < NT * PST / 8) *(uint4*)(Pd + c * 8) = make_uint4(0, 0, 0, 0);
  }
  {
    int chs = ch ^ rowin;           // swizzled k-chunk for K staging
#pragma unroll
    for (int it = 0; it < 7; ++it) {
      int jbase = it * 32 + w * 8;
      int j = jbase + rowin;
      int g;
      if (j < 80) g = n0 - 64 + j;
      else { int jj = j - 80; g = n0 - offsets[NDENSE + (jj >> 4)] + (jj & 15); }
      if (g < 0) g = 0;   // clamp; masked later
      async16(qkv + (size_t)g * LDQ + DIM + h * HDIM + chs * 8,
              KVbuf + jbase * HDIM + lane * 8);
    }
  }
  __syncthreads();

  // --- Phase 1: scores via MFMA, scatter banded entries to Sbuf ---
  for (int jb = w; jb < 14; jb += 4) {
    f32x4 acc = {};
#pragma unroll
    for (int kk = 0; kk < 2; ++kk) {
      bv8 a = *(const bv8*)(Qbuf + fr * QST + kk * 32 + fq * 8);
      bv8 b = *(const bv8*)(KVbuf + (jb * 16 + fr) * HDIM + ((kk * 4 + fq) ^ fr7) * 8);
      acc = __builtin_amdgcn_mfma_f32_16x16x32_bf16(a, b, acc, 0, 0, 0);
    }
    int j = jb * 16 + fr;           // K row this lane's column maps to
    if (jb < 5) {                   // dense region
      bool gvalid = (n0 - 64 + j) >= 0;
#pragma unroll
      for (int r = 0; r < 4; ++r) {
        int ni = fq * 4 + r;
        int o = ni + 64 - j;
        if (o >= 0 && o < NDENSE)
          Sbuf[ni][o] = gvalid ? acc[r] : -3.0e38f;
      }
    } else {                        // dyadic: only diagonal entries used
      int jj = j - 80;
      int s = jj >> 4, tni = jj & 15;
      int r = tni - fq * 4;
      if (r >= 0 && r < 4) {
        bool gvalid = (n0 + tni - offsets[NDENSE + s]) >= 0;
        Sbuf[tni][NDENSE + s] = gvalid ? acc[r] : -3.0e38f;
      }
    }
  }
  __syncthreads();   // all K reads done -> KVbuf reusable; Sbuf published

  // --- stage V into KVbuf (plain chunks); overlaps Phase-2 softmax ---
#pragma unroll
  for (int it = 0; it < 7; ++it) {
    int jbase = it * 32 + w * 8;
    int j = jbase + rowin;
    int g;
    if (j < 80) g = n0 - 64 + j;
    else { int jj = j - 80; g = n0 - offsets[NDENSE + (jj >> 4)] + (jj & 15); }
    if (g < 0) g = 0;
    async16(qkv + (size_t)g * LDQ + 2 * DIM + h * HDIM + ch * 8,
            KVbuf + jbase * HDIM + lane * 8);
  }

  // --- Phase 2: softmax (16 threads per row), banded P -> Pd (bf16) ---
  {
    int t = tid & 15, ni = tid >> 4;
    float sc5[5];
    float m = -3.0e38f;
#pragma unroll
    for (int k = 0; k < 5; ++k) {
      int o = t + k * 16;
      float v = -3.0e38f;
      if (o < NOFF) {
        float raw = Sbuf[ni][o];
        if (raw > -1.0e38f) v = raw * 0.125f + pos_bias[o * NHEAD + h];
      }
      sc5[k] = v;
      m = fmaxf(m, v);
    }
#pragma unroll
    for (int d = 1; d < 16; d <<= 1) m = fmaxf(m, __shfl_xor(m, d));
    float sum = 0.f;
#pragma unroll
    for (int k = 0; k < 5; ++k) {
      int o = t + k * 16;
      if (o < NOFF && sc5[k] > -1.0e38f) {
        float e = __expf(sc5[k] - m);
        sum += e;
        int j = (o < NDENSE) ? (ni + 64 - o) : (80 + (o - NDENSE) * 16 + ni);
        Pd[ni * PST + j] = (__bf16)e;
      }
    }
#pragma unroll
    for (int d = 1; d < 16; d <<= 1) sum += __shfl_xor(sum, d);
    if (t == 0) inv_l[ni] = 1.f / sum;
  }
  __syncthreads();   // drains V async16s (vmcnt 0) + publishes Pd/inv_l

  // --- Phase 3: PV via MFMA (each wave one 16-col d-tile) + gate epilogue ---
  {
    const int db = w;
    f32x4 acc = {};
#pragma unroll
    for (int kt = 0; kt < 7; ++kt) {
      bv8 a = *(const bv8*)(Pd + fr * PST + kt * 32 + fq * 8);
      bv8 b;
#pragma unroll
      for (int jj = 0; jj < 8; ++jj)
        b[jj] = KVbuf[(kt * 32 + fq * 8 + jj) * HDIM + db * 16 + fr];
      acc = __builtin_amdgcn_mfma_f32_16x16x32_bf16(a, b, acc, 0, 0, 0);
    }
    int d = db * 16 + fr;
#pragma unroll
    for (int r = 0; r < 4; ++r) {
      int ni = fq * 4 + r;
      float o = acc[r] * inv_l[ni];
      float gp = (float)qkv[(size_t)(n0 + ni) * LDQ + 3 * DIM + h * HDIM + d];
      float gate = 1.f / (1.f + __expf(-gp));
      fg[(size_t)(n0 + ni) * DIM + h * HDIM + d] = (__bf16)(o * gate);
    }
  }
}

// ---------------------------------------------------------------------------
extern "C" void kernel_launch(void* const* d_in, const int* in_sizes, int n_in,
                              void* d_out, int out_size, void* d_ws, size_t ws_size,
                              hipStream_t stream) {
  const float* x        = (const float*)d_in[0];
  const float* Wqkv     = (const float*)d_in[1];
  const float* bqkv     = (const float*)d_in[2];
  const float* Wgate    = (const float*)d_in[3];
  const float* bgate    = (const float*)d_in[4];
  const float* Wout     = (const float*)d_in[5];
  const float* bout     = (const float*)d_in[6];
  const float* pos_bias = (const float*)d_in[7];
  const int*   offsets  = (const int*)d_in[8];
  float* out = (float*)d_out;

  // workspace layout (bf16), cvt dst regions contiguous in this order
  __bf16* xb       = (__bf16*)d_ws;                               // 2048x1024
  __bf16* Wqkvb    = xb    + (size_t)SEQ_N * DIM;                 // 3072x1024
  __bf16* Wgateb   = Wqkvb + (size_t)3 * DIM * DIM;               // 1024x1024
  __bf16* Woutb    = Wgateb + (size_t)DIM * DIM;                  // 1024x1024
  __bf16* qkvg     = Woutb + (size_t)DIM * DIM;                   // 2048x4096
  __bf16* flatgate = qkvg + (size_t)SEQ_N * LDQ;                  // 2048x1024

  // 0) fp32 -> bf16 (single launch)
  cvt_all<<<dim3(E4 / 1024), dim3(256), 0, stream>>>(x, Wqkv, Wgate, Wout, xb);

  // 1) [qkv | gate_pre] = x @ [Wqkv;Wgate]^T + [bqkv;bgate]  -> bf16 qkvg
  gemm_bt<128, __bf16><<<dim3(LDQ / 128, SEQ_N / BM), dim3(256), 0, stream>>>(
      xb, Wqkvb, Wgateb, bqkv, bgate, 3 * DIM, qkvg, LDQ, DIM);

  // 2) attention + sigmoid-gate fuse -> flatgate (bf16)
  attn_mfma<<<dim3((SEQ_N / NT) * NHEAD), dim3(256), 0, stream>>>(
      qkvg, pos_bias, offsets, flatgate);

  // 3) out = flatgate @ Wout^T + bout  -> fp32 d_out (64x64 tiles: 512 blocks)
  gemm_bt64<float><<<dim3(DIM / 64, SEQ_N / 64), dim3(256), 0, stream>>>(
      flatgate, Woutb, bout, out, DIM, DIM);
}